// Round 8
// baseline (601.603 us; speedup 1.0000x reference)
//
#include <hip/hip_runtime.h>
#include <math.h>

#define N_NODES 20000
#define N_EDGES 640000
#define ETOT (N_EDGES + N_NODES)
#define HC 256
#define NLAYER 3
#define NBATCH 16
#define GEPS 1e-5f
#define NSLOT 64
#define L2E 1.44269504f

typedef unsigned short u16;
typedef unsigned int u32;
typedef __attribute__((ext_vector_type(8))) short short8;
typedef __attribute__((ext_vector_type(4))) float floatx4;

__device__ __forceinline__ u16 f2bf(float f) {
    u32 u = __float_as_uint(f);
    u32 r = (u + 0x7FFFu + ((u >> 16) & 1u)) >> 16;
    return (u16)r;
}

__device__ __forceinline__ float4 bf2f4(uint2 u) {
    float4 r;
    r.x = __uint_as_float(u.x << 16);
    r.y = __uint_as_float(u.x & 0xFFFF0000u);
    r.z = __uint_as_float(u.y << 16);
    r.w = __uint_as_float(u.y & 0xFFFF0000u);
    return r;
}

// VALU-only 16-lane butterfly sum
__device__ __forceinline__ float dpp_red16(float x) {
    x += __int_as_float(__builtin_amdgcn_update_dpp(0, __float_as_int(x), 0xB1, 0xF, 0xF, true));
    x += __int_as_float(__builtin_amdgcn_update_dpp(0, __float_as_int(x), 0x4E, 0xF, 0xF, true));
    x += __int_as_float(__builtin_amdgcn_update_dpp(0, __float_as_int(x), 0x141, 0xF, 0xF, true));
    x += __int_as_float(__builtin_amdgcn_update_dpp(0, __float_as_int(x), 0x140, 0xF, 0xF, true));
    return x;
}

// ---------------- prep: convert x to bf16, transpose W, zero scratch ----------------

__global__ __launch_bounds__(256) void prep(const float* __restrict__ x, u16* __restrict__ xbf,
                                            const float* __restrict__ Wl, const float* __restrict__ Wr,
                                            u16* __restrict__ WT, uint4* __restrict__ zbase, int zq) {
    int b = blockIdx.x, tid = threadIdx.x;
    if (b < 1000) {
        for (int i = b * 256 + tid; i < 640000; i += 256000) {
            const float4* x4 = (const float4*)x + (size_t)i * 2;
            float4 a = x4[0], c = x4[1];
            u16 o[8] = {f2bf(a.x), f2bf(a.y), f2bf(a.z), f2bf(a.w),
                        f2bf(c.x), f2bf(c.y), f2bf(c.z), f2bf(c.w)};
            ((uint4*)xbf)[i] = *(const uint4*)o;
        }
    } else if (b < 1384) {
        __shared__ float T[32][33];
        int bi = b - 1000;
        int kb = bi & 7, nbk = (bi >> 3) & 15, l = bi >> 7;
        int n0 = nbk * 32, k0 = kb * 32;
        const float* W = ((n0 < 256) ? Wl : Wr) + (size_t)l * 65536;
        int nn = n0 & 255;
        int tx = tid & 31, ty = tid >> 5;
        #pragma unroll
        for (int i = 0; i < 4; ++i)
            T[ty + i * 8][tx] = W[(size_t)(k0 + ty + i * 8) * 256 + nn + tx];
        __syncthreads();
        u16* outw = WT + (size_t)l * 512 * 256;
        #pragma unroll
        for (int i = 0; i < 4; ++i)
            outw[(size_t)(n0 + ty + i * 8) * 256 + k0 + tx] = f2bf(T[tx][ty + i * 8]);
    } else {
        uint4 z = make_uint4(0, 0, 0, 0);
        for (int i = (b - 1384) * 256 + tid; i < zq; i += 120 * 256) zbase[i] = z;
    }
}

// ---------------- CSR build: count / scan / scatter ----------------

__global__ void count_deg(const int* __restrict__ dst, int* __restrict__ deg) {
    int e = blockIdx.x * 256 + threadIdx.x;
    if (e < N_EDGES) atomicAdd(&deg[dst[e]], 1);
}

__global__ __launch_bounds__(1024) void scan_excl(int* __restrict__ data, int* __restrict__ cursor) {
    __shared__ int wsum[16];
    int t = threadIdx.x, lane = t & 63, wid = t >> 6;
    int i0 = t * 20;
    int d[20];
    int tot = 0;
    #pragma unroll
    for (int j = 0; j < 20; ++j) {
        int i = i0 + j;
        int v = (i < N_NODES) ? (data[i] + 1) : 0;  // +1 = self-loop
        d[j] = v;
        tot += v;
    }
    int x = tot;
    #pragma unroll
    for (int off = 1; off < 64; off <<= 1) {
        int tmp = __shfl_up(x, off);
        if (lane >= off) x += tmp;
    }
    if (lane == 63) wsum[wid] = x;
    __syncthreads();
    if (t == 0) {
        int run = 0;
        #pragma unroll
        for (int w = 0; w < 16; ++w) { int tv = wsum[w]; wsum[w] = run; run += tv; }
    }
    __syncthreads();
    int run = wsum[wid] + x - tot;
    #pragma unroll
    for (int j = 0; j < 20; ++j) {
        int i = i0 + j;
        if (i < N_NODES) { data[i] = run; cursor[i] = run; }
        run += d[j];
    }
    if (t == 0) data[N_NODES] = ETOT;
}

__global__ void scatter_edges(const int* __restrict__ src, const int* __restrict__ dst,
                              int* __restrict__ cursor, int* __restrict__ col) {
    int t = blockIdx.x * 256 + threadIdx.x;
    if (t < N_NODES) {
        int p = atomicAdd(&cursor[t], 1);
        col[p] = t;
    } else if (t < N_NODES + N_EDGES) {
        int e = t - N_NODES;
        int p = atomicAdd(&cursor[dst[e]], 1);
        col[p] = src[e];
    }
}

// ---------------- bf16 MFMA GEMM: 128x256 per block, 4 waves x (64x128) ----------------
// nstrip 0 -> xl (WT rows 0-255), 1 -> xr (WT rows 256-511). Pure GEMM, A pre-normalized.

__global__ __launch_bounds__(256) void gemm_mfma(
    const u16* __restrict__ Abf, const u16* __restrict__ WTl,
    const float* __restrict__ b0, const float* __restrict__ b1,
    u16* __restrict__ xlb, u16* __restrict__ xrb) {
    __shared__ u16 As[128][40];
    __shared__ u16 Bs[256][40];
    int row0 = blockIdx.x * 128;
    int nstrip = blockIdx.y;
    const float* bias = nstrip ? b1 : b0;
    u16* outp = nstrip ? xrb : xlb;
    const u16* Wbase = WTl + (size_t)nstrip * 256 * 256;

    int tid = threadIdx.x;
    int wave = tid >> 6, lane = tid & 63;
    int wm = (wave & 1) * 64, wn = (wave >> 1) * 128;
    int quad = lane >> 4, l16 = lane & 15;

    floatx4 acc[4][8] = {};

    int sra = tid >> 1;
    int sha = (tid & 1) * 16;

    for (int k0 = 0; k0 < 256; k0 += 32) {
        int gr = row0 + sra;
        uint4 av0 = make_uint4(0, 0, 0, 0), av1 = av0;
        if (gr < N_NODES) {
            const u16* p = Abf + (size_t)gr * 256 + k0 + sha;
            av0 = *(const uint4*)p;
            av1 = *(const uint4*)(p + 8);
        }
        const u16* q = Wbase + (size_t)tid * 256 + k0;
        uint4 bv0 = *(const uint4*)q;
        uint4 bv1 = *(const uint4*)(q + 8);
        uint4 bv2 = *(const uint4*)(q + 16);
        uint4 bv3 = *(const uint4*)(q + 24);
        *(uint4*)&As[sra][sha] = av0;
        *(uint4*)&As[sra][sha + 8] = av1;
        *(uint4*)&Bs[tid][0] = bv0;
        *(uint4*)&Bs[tid][8] = bv1;
        *(uint4*)&Bs[tid][16] = bv2;
        *(uint4*)&Bs[tid][24] = bv3;
        __syncthreads();

        short8 af[4], bfr[8];
        #pragma unroll
        for (int mi = 0; mi < 4; ++mi)
            af[mi] = *(const short8*)&As[wm + mi * 16 + l16][quad * 8];
        #pragma unroll
        for (int ni = 0; ni < 8; ++ni)
            bfr[ni] = *(const short8*)&Bs[wn + ni * 16 + l16][quad * 8];
        #pragma unroll
        for (int mi = 0; mi < 4; ++mi)
            #pragma unroll
            for (int ni = 0; ni < 8; ++ni)
                acc[mi][ni] = __builtin_amdgcn_mfma_f32_16x16x32_bf16(af[mi], bfr[ni], acc[mi][ni], 0, 0, 0);
        __syncthreads();
    }

    // C/D layout: col = lane&15, row = quad*4 + reg
    #pragma unroll
    for (int ni = 0; ni < 8; ++ni) {
        int col = wn + ni * 16 + l16;
        float bv = bias[col];
        #pragma unroll
        for (int mi = 0; mi < 4; ++mi) {
            int gr = row0 + wm + mi * 16 + quad * 4;
            #pragma unroll
            for (int r = 0; r < 4; ++r) {
                if (gr + r < N_NODES)
                    outp[(size_t)(gr + r) * 256 + col] = f2bf(acc[mi][ni][r] + bv);
            }
        }
    }
}

// ---------------- fused GATv2 aggregation + column stats ----------------
// 256 threads = 4 nodes per block; one wave per node; lane holds 4 channels.

__global__ __launch_bounds__(256) void gat_agg(
    const u16* __restrict__ xlb, const u16* __restrict__ xrb,
    const int* __restrict__ rowptr, const int* __restrict__ col,
    const float* __restrict__ att_l, const float* __restrict__ bias_l,
    u16* __restrict__ hB, float* __restrict__ slot) {
    __shared__ float sred[4][520];
    int wid = threadIdx.x >> 6, lane = threadIdx.x & 63;
    int node = blockIdx.x * 4 + wid;
    const uint2* xl2 = (const uint2*)xlb;
    float4 attv = ((const float4*)att_l)[lane];
    attv.x *= L2E; attv.y *= L2E; attv.z *= L2E; attv.w *= L2E;  // fold log2(e): exp(p)=exp2(p')
    float4 xrv = bf2f4(((const uint2*)xrb)[(size_t)node * 64 + lane]);
    int beg = rowptr[node], end = rowptr[node + 1];

    float denom = 0.f;
    float4 acc = make_float4(0.f, 0.f, 0.f, 0.f);

    int j = beg;
    for (; j + 8 <= end; j += 8) {
        int s[8];
        uint2 raw[8];
        float4 a[8];
        float p[8];
        #pragma unroll
        for (int u = 0; u < 8; ++u) s[u] = col[j + u];
        #pragma unroll
        for (int u = 0; u < 8; ++u) raw[u] = xl2[(size_t)s[u] * 64 + lane];
        #pragma unroll
        for (int u = 0; u < 8; ++u) {
            a[u] = bf2f4(raw[u]);
            float vx = a[u].x + xrv.x, vy = a[u].y + xrv.y;
            float vz = a[u].z + xrv.z, vw = a[u].w + xrv.w;
            vx = fmaxf(vx, 0.2f * vx);
            vy = fmaxf(vy, 0.2f * vy);
            vz = fmaxf(vz, 0.2f * vz);
            vw = fmaxf(vw, 0.2f * vw);
            p[u] = vx * attv.x + vy * attv.y + vz * attv.z + vw * attv.w;
        }
        #pragma unroll
        for (int u = 0; u < 8; ++u) p[u] = dpp_red16(p[u]);
        #pragma unroll
        for (int u = 0; u < 8; ++u) {
            float w = exp2f(p[u]);
            denom += w;
            acc.x += w * a[u].x; acc.y += w * a[u].y;
            acc.z += w * a[u].z; acc.w += w * a[u].w;
        }
    }
    for (; j < end; ++j) {
        int s = col[j];
        float4 a = bf2f4(xl2[(size_t)s * 64 + lane]);
        float vx = a.x + xrv.x, vy = a.y + xrv.y;
        float vz = a.z + xrv.z, vw = a.w + xrv.w;
        vx = fmaxf(vx, 0.2f * vx);
        vy = fmaxf(vy, 0.2f * vy);
        vz = fmaxf(vz, 0.2f * vz);
        vw = fmaxf(vw, 0.2f * vw);
        float p = vx * attv.x + vy * attv.y + vz * attv.z + vw * attv.w;
        p = dpp_red16(p);
        float w = exp2f(p);
        denom += w;
        acc.x += w * a.x; acc.y += w * a.y; acc.z += w * a.z; acc.w += w * a.w;
    }

    float inv = 1.f / denom;
    float4 b4 = ((const float4*)bias_l)[lane];
    float4 o;
    o.x = acc.x * inv + b4.x; o.y = acc.y * inv + b4.y;
    o.z = acc.z * inv + b4.z; o.w = acc.w * inv + b4.w;
    u16 ob[4] = {f2bf(o.x), f2bf(o.y), f2bf(o.z), f2bf(o.w)};
    ((uint2*)hB)[(size_t)node * 64 + lane] = *(const uint2*)ob;

    int cb2 = lane * 4;
    sred[wid][cb2 + 0] = o.x; sred[wid][cb2 + 1] = o.y;
    sred[wid][cb2 + 2] = o.z; sred[wid][cb2 + 3] = o.w;
    sred[wid][256 + cb2 + 0] = o.x * o.x; sred[wid][256 + cb2 + 1] = o.y * o.y;
    sred[wid][256 + cb2 + 2] = o.z * o.z; sred[wid][256 + cb2 + 3] = o.w * o.w;
    __syncthreads();
    int t = threadIdx.x;
    #pragma unroll
    for (int h = 0; h < 2; ++h) {
        int idx = t + h * 256;
        float s = sred[0][idx] + sred[1][idx] + sred[2][idx] + sred[3][idx];
        atomicAdd(&slot[(blockIdx.x & (NSLOT - 1)) * 512 + idx], s);
    }
}

// ---------------- finalize stats: slots -> per-channel scale/shift ----------------

__global__ __launch_bounds__(256) void fin_stats(const float* __restrict__ slot,
                                                 const float* __restrict__ nw, const float* __restrict__ nb,
                                                 const float* __restrict__ na,
                                                 float* __restrict__ wcbb) {
    int c = threadIdx.x;
    float sum = 0.f, sq = 0.f;
    for (int s = 0; s < NSLOT; ++s) {
        sum += slot[s * 512 + c];
        sq += slot[s * 512 + 256 + c];
    }
    const float invn = 1.f / (float)N_NODES;
    float mean = sum * invn, Eh2 = sq * invn;
    float a = na[c];
    float var = Eh2 - (2.f * a - a * a) * mean * mean;
    float wc = nw[c] * rsqrtf(var + GEPS);
    wcbb[c] = wc;
    wcbb[256 + c] = nb[c] - a * mean * wc;
}

// ---------------- GraphNorm + PReLU: hB(bf16) -> hbf(bf16), 8 rows/block ----------------

__global__ __launch_bounds__(256) void norm_prelu(const u16* __restrict__ hB, u16* __restrict__ hbf,
                                                  const float* __restrict__ wcbb,
                                                  const float* __restrict__ pa, int l) {
    int t = threadIdx.x;
    int row = blockIdx.x * 8 + (t >> 5);
    int c = (t & 31) * 8;
    float ap = pa[l];
    float4 wc0 = *(const float4*)&wcbb[c];
    float4 wc1 = *(const float4*)&wcbb[c + 4];
    float4 bb0 = *(const float4*)&wcbb[256 + c];
    float4 bb1 = *(const float4*)&wcbb[256 + c + 4];
    uint4 raw = ((const uint4*)hB)[(size_t)row * 32 + (c >> 3)];
    float4 a = bf2f4(make_uint2(raw.x, raw.y));
    float4 b = bf2f4(make_uint2(raw.z, raw.w));
    a.x = a.x * wc0.x + bb0.x; a.y = a.y * wc0.y + bb0.y;
    a.z = a.z * wc0.z + bb0.z; a.w = a.w * wc0.w + bb0.w;
    b.x = b.x * wc1.x + bb1.x; b.y = b.y * wc1.y + bb1.y;
    b.z = b.z * wc1.z + bb1.z; b.w = b.w * wc1.w + bb1.w;
    a.x = fmaxf(a.x, ap * a.x); a.y = fmaxf(a.y, ap * a.y);
    a.z = fmaxf(a.z, ap * a.z); a.w = fmaxf(a.w, ap * a.w);
    b.x = fmaxf(b.x, ap * b.x); b.y = fmaxf(b.y, ap * b.y);
    b.z = fmaxf(b.z, ap * b.z); b.w = fmaxf(b.w, ap * b.w);
    u16 o[8] = {f2bf(a.x), f2bf(a.y), f2bf(a.z), f2bf(a.w),
                f2bf(b.x), f2bf(b.y), f2bf(b.z), f2bf(b.w)};
    ((uint4*)hbf)[(size_t)row * 32 + (c >> 3)] = *(const uint4*)o;
}

// ---------------- pool with fused final GraphNorm+PReLU ----------------

__global__ __launch_bounds__(256) void pool_kernel(const u16* __restrict__ hB,
                                                   const int* __restrict__ batch,
                                                   const float* __restrict__ slots2,
                                                   const float* __restrict__ nw, const float* __restrict__ nb,
                                                   const float* __restrict__ na, const float* __restrict__ pa,
                                                   float* __restrict__ pooled) {
    __shared__ float accs[NBATCH][256];
    int c = threadIdx.x;
    float sum = 0.f, sq = 0.f;
    for (int s = 0; s < NSLOT; ++s) {
        sum += slots2[s * 512 + c];
        sq += slots2[s * 512 + 256 + c];
    }
    const float invn = 1.f / (float)N_NODES;
    float mean = sum * invn, Eh2 = sq * invn;
    float a = na[c];
    float var = Eh2 - (2.f * a - a * a) * mean * mean;
    float wc = nw[c] * rsqrtf(var + GEPS);
    float bb = nb[c] - a * mean * wc;
    float ap = pa[2];

    #pragma unroll
    for (int b = 0; b < NBATCH; ++b) accs[b][c] = 0.f;
    int r0 = blockIdx.x * 100;
    int r1 = min(N_NODES, r0 + 100);
    for (int i = r0; i < r1; ++i) {
        float v = __uint_as_float(((u32)hB[(size_t)i * 256 + c]) << 16);
        v = v * wc + bb;
        v = fmaxf(v, ap * v);
        accs[batch[i]][c] += v;
    }
    int bmin = batch[r0], bmax = batch[r1 - 1];
    for (int b = bmin; b <= bmax; ++b) atomicAdd(&pooled[b * 256 + c], accs[b][c]);
}

// ---------------- pooled GraphNorm (1 block) ----------------

__global__ __launch_bounds__(256) void pool_norm(const float* __restrict__ pooled,
                                                 const float* __restrict__ nw, const float* __restrict__ nb,
                                                 const float* __restrict__ na,
                                                 float* __restrict__ pn) {
    int c = threadIdx.x;
    float mean = 0.f, sq = 0.f;
    #pragma unroll
    for (int i = 0; i < NBATCH; ++i) {
        float v = pooled[i * 256 + c];
        mean += v; sq += v * v;
    }
    mean *= (1.f / NBATCH); sq *= (1.f / NBATCH);
    float a = na[c];
    float var = sq - (2.f * a - a * a) * mean * mean;
    float wc = nw[c] * rsqrtf(var + GEPS);
    float bb = nb[c] - a * mean * wc;
    #pragma unroll
    for (int i = 0; i < NBATCH; ++i)
        pn[i * 256 + c] = pooled[i * 256 + c] * wc + bb;
}

// ---------------- FC ----------------

__global__ __launch_bounds__(256) void fc_kernel(const float* __restrict__ pn,
                                                 const float* __restrict__ fcW, const float* __restrict__ fcb,
                                                 float* __restrict__ out) {
    __shared__ float pnl[256];
    __shared__ float part[128];
    int b = blockIdx.x;
    int t = threadIdx.x;
    pnl[t] = pn[b * 256 + t];
    __syncthreads();
    int o = t & 127, half = t >> 7;
    float s = 0.f;
    int kbase = half * 128;
    #pragma unroll 8
    for (int k = 0; k < 128; ++k)
        s += pnl[kbase + k] * fcW[(kbase + k) * 128 + o];
    if (half == 1) part[o] = s;
    __syncthreads();
    if (half == 0) out[b * 128 + o] = s + part[o] + fcb[o];
}

// ---------------- launch ----------------

extern "C" void kernel_launch(void* const* d_in, const int* in_sizes, int n_in,
                              void* d_out, int out_size, void* d_ws, size_t ws_size,
                              hipStream_t stream) {
    const float* x    = (const float*)d_in[0];
    const int*   ei   = (const int*)d_in[1];
    const int*   batch= (const int*)d_in[2];
    const float* Wl   = (const float*)d_in[3];
    const float* bl   = (const float*)d_in[4];
    const float* Wr   = (const float*)d_in[5];
    const float* br   = (const float*)d_in[6];
    const float* att  = (const float*)d_in[7];
    const float* cb   = (const float*)d_in[8];
    const float* pa   = (const float*)d_in[9];
    const float* nw   = (const float*)d_in[10];
    const float* nb   = (const float*)d_in[11];
    const float* na   = (const float*)d_in[12];
    const float* fcW  = (const float*)d_in[13];
    const float* fcb  = (const float*)d_in[14];
    float* out = (float*)d_out;

    char* ws = (char*)d_ws;
    size_t off = 0;
    auto carve = [&](size_t bytes) -> void* {
        void* p = (void*)(ws + off);
        off += (bytes + 255) & ~(size_t)255;
        return p;
    };
    // zero-span region (prep zeroes [rowptr, end-of-pooled))
    size_t z0 = off;
    int*   rowptr = (int*)carve((N_NODES + 1) * sizeof(int));
    float* slots  = (float*)carve((size_t)NLAYER * NSLOT * 512 * sizeof(float));
    float* pooled = (float*)carve(NBATCH * HC * sizeof(float));
    size_t z1 = off;
    // non-zeroed scratch
    int*   cursor = (int*)carve(N_NODES * sizeof(int));
    int*   colidx = (int*)carve((size_t)ETOT * sizeof(int));
    u16*   xlb    = (u16*)carve((size_t)N_NODES * HC * sizeof(u16));
    u16*   xrb    = (u16*)carve((size_t)N_NODES * HC * sizeof(u16));
    u16*   hB     = (u16*)carve((size_t)N_NODES * HC * sizeof(u16));
    u16*   xbf    = (u16*)carve((size_t)N_NODES * HC * sizeof(u16));
    u16*   hbf    = (u16*)carve((size_t)N_NODES * HC * sizeof(u16));
    u16*   WT     = (u16*)carve((size_t)NLAYER * 512 * 256 * sizeof(u16));
    float* wcbb   = (float*)carve(512 * sizeof(float));
    float* pn     = (float*)carve(NBATCH * HC * sizeof(float));

    int zq = (int)((z1 - z0) / 16);
    const int* srcp = ei;
    const int* dstp = ei + N_EDGES;

    prep<<<1504, 256, 0, stream>>>(x, xbf, Wl, Wr, WT, (uint4*)(ws + z0), zq);
    count_deg<<<(N_EDGES + 255) / 256, 256, 0, stream>>>(dstp, rowptr);
    scan_excl<<<1, 1024, 0, stream>>>(rowptr, cursor);
    scatter_edges<<<(ETOT + 255) / 256, 256, 0, stream>>>(srcp, dstp, cursor, colidx);

    for (int l = 0; l < NLAYER; ++l) {
        const u16* Asrc = (l == 0) ? xbf : hbf;
        gemm_mfma<<<dim3(157, 2), 256, 0, stream>>>(Asrc, WT + (size_t)l * 512 * 256,
                                                    bl + l * 256, br + l * 256, xlb, xrb);
        gat_agg<<<5000, 256, 0, stream>>>(xlb, xrb, rowptr, colidx, att + l * 256, cb + l * 256,
                                          hB, slots + (size_t)l * NSLOT * 512);
        if (l < NLAYER - 1) {
            fin_stats<<<1, 256, 0, stream>>>(slots + (size_t)l * NSLOT * 512, nw, nb, na, wcbb);
            norm_prelu<<<2500, 256, 0, stream>>>(hB, hbf, wcbb, pa, l);
        }
    }
    pool_kernel<<<200, 256, 0, stream>>>(hB, batch, slots + (size_t)2 * NSLOT * 512,
                                         nw, nb, na, pa, pooled);
    pool_norm<<<1, 256, 0, stream>>>(pooled, nw, nb, na, pn);
    fc_kernel<<<NBATCH, 256, 0, stream>>>(pn, fcW, fcb, out);
}

// Round 9
// 532.321 us; speedup vs baseline: 1.1302x; 1.1302x over previous
//
#include <hip/hip_runtime.h>
#include <math.h>

#define N_NODES 20000
#define N_EDGES 640000
#define ETOT (N_EDGES + N_NODES)
#define HC 256
#define NLAYER 3
#define NBATCH 16
#define GEPS 1e-5f
#define NSLOT 64
#define L2E 1.44269504f

typedef unsigned short u16;
typedef unsigned int u32;
typedef __attribute__((ext_vector_type(8))) short short8;
typedef __attribute__((ext_vector_type(4))) float floatx4;

__device__ __forceinline__ u16 f2bf(float f) {
    u32 u = __float_as_uint(f);
    u32 r = (u + 0x7FFFu + ((u >> 16) & 1u)) >> 16;
    return (u16)r;
}

__device__ __forceinline__ float4 bf2f4(uint2 u) {
    float4 r;
    r.x = __uint_as_float(u.x << 16);
    r.y = __uint_as_float(u.x & 0xFFFF0000u);
    r.z = __uint_as_float(u.y << 16);
    r.w = __uint_as_float(u.y & 0xFFFF0000u);
    return r;
}

// VALU-only 16-lane butterfly sum
__device__ __forceinline__ float dpp_red16(float x) {
    x += __int_as_float(__builtin_amdgcn_update_dpp(0, __float_as_int(x), 0xB1, 0xF, 0xF, true));
    x += __int_as_float(__builtin_amdgcn_update_dpp(0, __float_as_int(x), 0x4E, 0xF, 0xF, true));
    x += __int_as_float(__builtin_amdgcn_update_dpp(0, __float_as_int(x), 0x141, 0xF, 0xF, true));
    x += __int_as_float(__builtin_amdgcn_update_dpp(0, __float_as_int(x), 0x140, 0xF, 0xF, true));
    return x;
}

// ---------------- prep: convert x to bf16, transpose W, zero scratch ----------------

__global__ __launch_bounds__(256) void prep(const float* __restrict__ x, u16* __restrict__ xbf,
                                            const float* __restrict__ Wl, const float* __restrict__ Wr,
                                            u16* __restrict__ WT, uint4* __restrict__ zbase, int zq) {
    int b = blockIdx.x, tid = threadIdx.x;
    if (b < 1000) {
        for (int i = b * 256 + tid; i < 640000; i += 256000) {
            const float4* x4 = (const float4*)x + (size_t)i * 2;
            float4 a = x4[0], c = x4[1];
            u16 o[8] = {f2bf(a.x), f2bf(a.y), f2bf(a.z), f2bf(a.w),
                        f2bf(c.x), f2bf(c.y), f2bf(c.z), f2bf(c.w)};
            ((uint4*)xbf)[i] = *(const uint4*)o;
        }
    } else if (b < 1384) {
        __shared__ float T[32][33];
        int bi = b - 1000;
        int kb = bi & 7, nbk = (bi >> 3) & 15, l = bi >> 7;
        int n0 = nbk * 32, k0 = kb * 32;
        const float* W = ((n0 < 256) ? Wl : Wr) + (size_t)l * 65536;
        int nn = n0 & 255;
        int tx = tid & 31, ty = tid >> 5;
        #pragma unroll
        for (int i = 0; i < 4; ++i)
            T[ty + i * 8][tx] = W[(size_t)(k0 + ty + i * 8) * 256 + nn + tx];
        __syncthreads();
        u16* outw = WT + (size_t)l * 512 * 256;
        #pragma unroll
        for (int i = 0; i < 4; ++i)
            outw[(size_t)(n0 + ty + i * 8) * 256 + k0 + tx] = f2bf(T[tx][ty + i * 8]);
    } else {
        uint4 z = make_uint4(0, 0, 0, 0);
        for (int i = (b - 1384) * 256 + tid; i < zq; i += 120 * 256) zbase[i] = z;
    }
}

// ---------------- CSR build: count / scan / scatter ----------------

__global__ void count_deg(const int* __restrict__ dst, int* __restrict__ deg) {
    int e = blockIdx.x * 256 + threadIdx.x;
    if (e < N_EDGES) atomicAdd(&deg[dst[e]], 1);
}

__global__ __launch_bounds__(1024) void scan_excl(int* __restrict__ data, int* __restrict__ cursor) {
    __shared__ int wsum[16];
    int t = threadIdx.x, lane = t & 63, wid = t >> 6;
    int i0 = t * 20;
    int d[20];
    int tot = 0;
    #pragma unroll
    for (int j = 0; j < 20; ++j) {
        int i = i0 + j;
        int v = (i < N_NODES) ? (data[i] + 1) : 0;  // +1 = self-loop
        d[j] = v;
        tot += v;
    }
    int x = tot;
    #pragma unroll
    for (int off = 1; off < 64; off <<= 1) {
        int tmp = __shfl_up(x, off);
        if (lane >= off) x += tmp;
    }
    if (lane == 63) wsum[wid] = x;
    __syncthreads();
    if (t == 0) {
        int run = 0;
        #pragma unroll
        for (int w = 0; w < 16; ++w) { int tv = wsum[w]; wsum[w] = run; run += tv; }
    }
    __syncthreads();
    int run = wsum[wid] + x - tot;
    #pragma unroll
    for (int j = 0; j < 20; ++j) {
        int i = i0 + j;
        if (i < N_NODES) { data[i] = run; cursor[i] = run; }
        run += d[j];
    }
    if (t == 0) data[N_NODES] = ETOT;
}

__global__ void scatter_edges(const int* __restrict__ src, const int* __restrict__ dst,
                              int* __restrict__ cursor, int* __restrict__ col) {
    int t = blockIdx.x * 256 + threadIdx.x;
    if (t < N_NODES) {
        int p = atomicAdd(&cursor[t], 1);
        col[p] = t;
    } else if (t < N_NODES + N_EDGES) {
        int e = t - N_NODES;
        int p = atomicAdd(&cursor[dst[e]], 1);
        col[p] = src[e];
    }
}

// ---------------- LDS-free direct-fragment bf16 MFMA GEMM ----------------
// grid (157, 4): 128 rows x 128 cols per block; 4 waves each 64x64.
// A fragment loaded straight from global: A[m=lane&15][k=quad*8+j] matches
// row-major bf16 A; B fragment = WT[n][k] rows (pre-transposed). No LDS, no barriers.

__global__ __launch_bounds__(256) void gemm_mfma(
    const u16* __restrict__ Abf, const u16* __restrict__ WT3,
    const float* __restrict__ b0, const float* __restrict__ b1,
    u16* __restrict__ xlb, u16* __restrict__ xrb) {
    int row0 = blockIdx.x * 128;
    int strip = blockIdx.y;                  // 0,1 -> xl; 2,3 -> xr
    const float* bias = (strip < 2) ? b0 : b1;
    u16* outp = (strip < 2) ? xlb : xrb;
    int c0 = (strip & 1) * 128;
    const u16* Wbase = WT3 + (size_t)strip * 128 * 256;

    int tid = threadIdx.x;
    int wave = tid >> 6, lane = tid & 63;
    int wm = (wave & 1) * 64, wn = (wave >> 1) * 64;
    int quad = lane >> 4, l16 = lane & 15;

    floatx4 acc[4][4] = {};
    const u16* pA[4];
    const u16* pB[4];
    #pragma unroll
    for (int mi = 0; mi < 4; ++mi) {
        int r = row0 + wm + mi * 16 + l16;
        r = min(r, N_NODES - 1);             // clamp: OOB rows load valid junk, stores guarded
        pA[mi] = Abf + (size_t)r * 256 + quad * 8;
    }
    #pragma unroll
    for (int ni = 0; ni < 4; ++ni)
        pB[ni] = Wbase + (size_t)(wn + ni * 16 + l16) * 256 + quad * 8;

    #pragma unroll 2
    for (int k0 = 0; k0 < 256; k0 += 32) {
        short8 af[4], bf[4];
        #pragma unroll
        for (int mi = 0; mi < 4; ++mi) af[mi] = *(const short8*)(pA[mi] + k0);
        #pragma unroll
        for (int ni = 0; ni < 4; ++ni) bf[ni] = *(const short8*)(pB[ni] + k0);
        #pragma unroll
        for (int mi = 0; mi < 4; ++mi)
            #pragma unroll
            for (int ni = 0; ni < 4; ++ni)
                acc[mi][ni] = __builtin_amdgcn_mfma_f32_16x16x32_bf16(af[mi], bf[ni], acc[mi][ni], 0, 0, 0);
    }

    // C/D layout: col = lane&15, row = quad*4 + reg
    #pragma unroll
    for (int ni = 0; ni < 4; ++ni) {
        int col = c0 + wn + ni * 16 + l16;
        float bv = bias[col];
        #pragma unroll
        for (int mi = 0; mi < 4; ++mi) {
            int gr = row0 + wm + mi * 16 + quad * 4;
            #pragma unroll
            for (int r = 0; r < 4; ++r) {
                if (gr + r < N_NODES)
                    outp[(size_t)(gr + r) * 256 + col] = f2bf(acc[mi][ni][r] + bv);
            }
        }
    }
}

// ---------------- fused GATv2 aggregation + column stats ----------------
// 256 threads = 4 nodes per block; one wave per node; lane holds 4 channels.

__global__ __launch_bounds__(256) void gat_agg(
    const u16* __restrict__ xlb, const u16* __restrict__ xrb,
    const int* __restrict__ rowptr, const int* __restrict__ col,
    const float* __restrict__ att_l, const float* __restrict__ bias_l,
    u16* __restrict__ hB, float* __restrict__ slot) {
    __shared__ float sred[4][520];
    int wid = threadIdx.x >> 6, lane = threadIdx.x & 63;
    int node = blockIdx.x * 4 + wid;
    const uint2* xl2 = (const uint2*)xlb;
    float4 attv = ((const float4*)att_l)[lane];
    attv.x *= L2E; attv.y *= L2E; attv.z *= L2E; attv.w *= L2E;  // exp(p)=exp2(p*log2e)
    float4 xrv = bf2f4(((const uint2*)xrb)[(size_t)node * 64 + lane]);
    int beg = rowptr[node], end = rowptr[node + 1];

    float denom = 0.f;
    float4 acc = make_float4(0.f, 0.f, 0.f, 0.f);

    int j = beg;
    for (; j + 8 <= end; j += 8) {
        int s[8];
        uint2 raw[8];
        float4 a[8];
        float p[8];
        #pragma unroll
        for (int u = 0; u < 8; ++u) s[u] = col[j + u];
        #pragma unroll
        for (int u = 0; u < 8; ++u) raw[u] = xl2[(size_t)s[u] * 64 + lane];
        #pragma unroll
        for (int u = 0; u < 8; ++u) {
            a[u] = bf2f4(raw[u]);
            float vx = a[u].x + xrv.x, vy = a[u].y + xrv.y;
            float vz = a[u].z + xrv.z, vw = a[u].w + xrv.w;
            vx = fmaxf(vx, 0.2f * vx);
            vy = fmaxf(vy, 0.2f * vy);
            vz = fmaxf(vz, 0.2f * vz);
            vw = fmaxf(vw, 0.2f * vw);
            p[u] = vx * attv.x + vy * attv.y + vz * attv.z + vw * attv.w;
        }
        #pragma unroll
        for (int u = 0; u < 8; ++u) p[u] = dpp_red16(p[u]);
        #pragma unroll
        for (int u = 0; u < 8; ++u) {
            float w = exp2f(p[u]);
            denom += w;
            acc.x += w * a[u].x; acc.y += w * a[u].y;
            acc.z += w * a[u].z; acc.w += w * a[u].w;
        }
    }
    for (; j < end; ++j) {
        int s = col[j];
        float4 a = bf2f4(xl2[(size_t)s * 64 + lane]);
        float vx = a.x + xrv.x, vy = a.y + xrv.y;
        float vz = a.z + xrv.z, vw = a.w + xrv.w;
        vx = fmaxf(vx, 0.2f * vx);
        vy = fmaxf(vy, 0.2f * vy);
        vz = fmaxf(vz, 0.2f * vz);
        vw = fmaxf(vw, 0.2f * vw);
        float p = vx * attv.x + vy * attv.y + vz * attv.z + vw * attv.w;
        p = dpp_red16(p);
        float w = exp2f(p);
        denom += w;
        acc.x += w * a.x; acc.y += w * a.y; acc.z += w * a.z; acc.w += w * a.w;
    }

    float inv = 1.f / denom;
    float4 b4 = ((const float4*)bias_l)[lane];
    float4 o;
    o.x = acc.x * inv + b4.x; o.y = acc.y * inv + b4.y;
    o.z = acc.z * inv + b4.z; o.w = acc.w * inv + b4.w;
    u16 ob[4] = {f2bf(o.x), f2bf(o.y), f2bf(o.z), f2bf(o.w)};
    ((uint2*)hB)[(size_t)node * 64 + lane] = *(const uint2*)ob;

    int cb2 = lane * 4;
    sred[wid][cb2 + 0] = o.x; sred[wid][cb2 + 1] = o.y;
    sred[wid][cb2 + 2] = o.z; sred[wid][cb2 + 3] = o.w;
    sred[wid][256 + cb2 + 0] = o.x * o.x; sred[wid][256 + cb2 + 1] = o.y * o.y;
    sred[wid][256 + cb2 + 2] = o.z * o.z; sred[wid][256 + cb2 + 3] = o.w * o.w;
    __syncthreads();
    int t = threadIdx.x;
    #pragma unroll
    for (int h = 0; h < 2; ++h) {
        int idx = t + h * 256;
        float s = sred[0][idx] + sred[1][idx] + sred[2][idx] + sred[3][idx];
        atomicAdd(&slot[(blockIdx.x & (NSLOT - 1)) * 512 + idx], s);
    }
}

// ---------------- finalize stats: slots -> per-channel scale/shift ----------------

__global__ __launch_bounds__(256) void fin_stats(const float* __restrict__ slot,
                                                 const float* __restrict__ nw, const float* __restrict__ nb,
                                                 const float* __restrict__ na,
                                                 float* __restrict__ wcbb) {
    int c = threadIdx.x;
    float sum = 0.f, sq = 0.f;
    for (int s = 0; s < NSLOT; ++s) {
        sum += slot[s * 512 + c];
        sq += slot[s * 512 + 256 + c];
    }
    const float invn = 1.f / (float)N_NODES;
    float mean = sum * invn, Eh2 = sq * invn;
    float a = na[c];
    float var = Eh2 - (2.f * a - a * a) * mean * mean;
    float wc = nw[c] * rsqrtf(var + GEPS);
    wcbb[c] = wc;
    wcbb[256 + c] = nb[c] - a * mean * wc;
}

// ---------------- GraphNorm + PReLU: hB(bf16) -> hbf(bf16), 8 rows/block ----------------

__global__ __launch_bounds__(256) void norm_prelu(const u16* __restrict__ hB, u16* __restrict__ hbf,
                                                  const float* __restrict__ wcbb,
                                                  const float* __restrict__ pa, int l) {
    int t = threadIdx.x;
    int row = blockIdx.x * 8 + (t >> 5);
    int c = (t & 31) * 8;
    float ap = pa[l];
    float4 wc0 = *(const float4*)&wcbb[c];
    float4 wc1 = *(const float4*)&wcbb[c + 4];
    float4 bb0 = *(const float4*)&wcbb[256 + c];
    float4 bb1 = *(const float4*)&wcbb[256 + c + 4];
    uint4 raw = ((const uint4*)hB)[(size_t)row * 32 + (c >> 3)];
    float4 a = bf2f4(make_uint2(raw.x, raw.y));
    float4 b = bf2f4(make_uint2(raw.z, raw.w));
    a.x = a.x * wc0.x + bb0.x; a.y = a.y * wc0.y + bb0.y;
    a.z = a.z * wc0.z + bb0.z; a.w = a.w * wc0.w + bb0.w;
    b.x = b.x * wc1.x + bb1.x; b.y = b.y * wc1.y + bb1.y;
    b.z = b.z * wc1.z + bb1.z; b.w = b.w * wc1.w + bb1.w;
    a.x = fmaxf(a.x, ap * a.x); a.y = fmaxf(a.y, ap * a.y);
    a.z = fmaxf(a.z, ap * a.z); a.w = fmaxf(a.w, ap * a.w);
    b.x = fmaxf(b.x, ap * b.x); b.y = fmaxf(b.y, ap * b.y);
    b.z = fmaxf(b.z, ap * b.z); b.w = fmaxf(b.w, ap * b.w);
    u16 o[8] = {f2bf(a.x), f2bf(a.y), f2bf(a.z), f2bf(a.w),
                f2bf(b.x), f2bf(b.y), f2bf(b.z), f2bf(b.w)};
    ((uint4*)hbf)[(size_t)row * 32 + (c >> 3)] = *(const uint4*)o;
}

// ---------------- pool with fused final GraphNorm+PReLU ----------------

__global__ __launch_bounds__(256) void pool_kernel(const u16* __restrict__ hB,
                                                   const int* __restrict__ batch,
                                                   const float* __restrict__ slots2,
                                                   const float* __restrict__ nw, const float* __restrict__ nb,
                                                   const float* __restrict__ na, const float* __restrict__ pa,
                                                   float* __restrict__ pooled) {
    __shared__ float accs[NBATCH][256];
    int c = threadIdx.x;
    float sum = 0.f, sq = 0.f;
    for (int s = 0; s < NSLOT; ++s) {
        sum += slots2[s * 512 + c];
        sq += slots2[s * 512 + 256 + c];
    }
    const float invn = 1.f / (float)N_NODES;
    float mean = sum * invn, Eh2 = sq * invn;
    float a = na[c];
    float var = Eh2 - (2.f * a - a * a) * mean * mean;
    float wc = nw[c] * rsqrtf(var + GEPS);
    float bb = nb[c] - a * mean * wc;
    float ap = pa[2];

    #pragma unroll
    for (int b = 0; b < NBATCH; ++b) accs[b][c] = 0.f;
    int r0 = blockIdx.x * 100;
    int r1 = min(N_NODES, r0 + 100);
    for (int i = r0; i < r1; ++i) {
        float v = __uint_as_float(((u32)hB[(size_t)i * 256 + c]) << 16);
        v = v * wc + bb;
        v = fmaxf(v, ap * v);
        accs[batch[i]][c] += v;
    }
    int bmin = batch[r0], bmax = batch[r1 - 1];
    for (int b = bmin; b <= bmax; ++b) atomicAdd(&pooled[b * 256 + c], accs[b][c]);
}

// ---------------- pooled GraphNorm (1 block) ----------------

__global__ __launch_bounds__(256) void pool_norm(const float* __restrict__ pooled,
                                                 const float* __restrict__ nw, const float* __restrict__ nb,
                                                 const float* __restrict__ na,
                                                 float* __restrict__ pn) {
    int c = threadIdx.x;
    float mean = 0.f, sq = 0.f;
    #pragma unroll
    for (int i = 0; i < NBATCH; ++i) {
        float v = pooled[i * 256 + c];
        mean += v; sq += v * v;
    }
    mean *= (1.f / NBATCH); sq *= (1.f / NBATCH);
    float a = na[c];
    float var = sq - (2.f * a - a * a) * mean * mean;
    float wc = nw[c] * rsqrtf(var + GEPS);
    float bb = nb[c] - a * mean * wc;
    #pragma unroll
    for (int i = 0; i < NBATCH; ++i)
        pn[i * 256 + c] = pooled[i * 256 + c] * wc + bb;
}

// ---------------- FC ----------------

__global__ __launch_bounds__(256) void fc_kernel(const float* __restrict__ pn,
                                                 const float* __restrict__ fcW, const float* __restrict__ fcb,
                                                 float* __restrict__ out) {
    __shared__ float pnl[256];
    __shared__ float part[128];
    int b = blockIdx.x;
    int t = threadIdx.x;
    pnl[t] = pn[b * 256 + t];
    __syncthreads();
    int o = t & 127, half = t >> 7;
    float s = 0.f;
    int kbase = half * 128;
    #pragma unroll 8
    for (int k = 0; k < 128; ++k)
        s += pnl[kbase + k] * fcW[(kbase + k) * 128 + o];
    if (half == 1) part[o] = s;
    __syncthreads();
    if (half == 0) out[b * 128 + o] = s + part[o] + fcb[o];
}

// ---------------- launch ----------------

extern "C" void kernel_launch(void* const* d_in, const int* in_sizes, int n_in,
                              void* d_out, int out_size, void* d_ws, size_t ws_size,
                              hipStream_t stream) {
    const float* x    = (const float*)d_in[0];
    const int*   ei   = (const int*)d_in[1];
    const int*   batch= (const int*)d_in[2];
    const float* Wl   = (const float*)d_in[3];
    const float* bl   = (const float*)d_in[4];
    const float* Wr   = (const float*)d_in[5];
    const float* br   = (const float*)d_in[6];
    const float* att  = (const float*)d_in[7];
    const float* cb   = (const float*)d_in[8];
    const float* pa   = (const float*)d_in[9];
    const float* nw   = (const float*)d_in[10];
    const float* nb   = (const float*)d_in[11];
    const float* na   = (const float*)d_in[12];
    const float* fcW  = (const float*)d_in[13];
    const float* fcb  = (const float*)d_in[14];
    float* out = (float*)d_out;

    char* ws = (char*)d_ws;
    size_t off = 0;
    auto carve = [&](size_t bytes) -> void* {
        void* p = (void*)(ws + off);
        off += (bytes + 255) & ~(size_t)255;
        return p;
    };
    // zero-span region (prep zeroes [rowptr, end-of-pooled))
    size_t z0 = off;
    int*   rowptr = (int*)carve((N_NODES + 1) * sizeof(int));
    float* slots  = (float*)carve((size_t)NLAYER * NSLOT * 512 * sizeof(float));
    float* pooled = (float*)carve(NBATCH * HC * sizeof(float));
    size_t z1 = off;
    // non-zeroed scratch
    int*   cursor = (int*)carve(N_NODES * sizeof(int));
    int*   colidx = (int*)carve((size_t)ETOT * sizeof(int));
    u16*   xlb    = (u16*)carve((size_t)N_NODES * HC * sizeof(u16));
    u16*   xrb    = (u16*)carve((size_t)N_NODES * HC * sizeof(u16));
    u16*   hB     = (u16*)carve((size_t)N_NODES * HC * sizeof(u16));
    u16*   xbf    = (u16*)carve((size_t)N_NODES * HC * sizeof(u16));
    u16*   hbf    = (u16*)carve((size_t)N_NODES * HC * sizeof(u16));
    u16*   WT     = (u16*)carve((size_t)NLAYER * 512 * 256 * sizeof(u16));
    float* wcbb   = (float*)carve(512 * sizeof(float));
    float* pn     = (float*)carve(NBATCH * HC * sizeof(float));

    int zq = (int)((z1 - z0) / 16);
    const int* srcp = ei;
    const int* dstp = ei + N_EDGES;

    prep<<<1504, 256, 0, stream>>>(x, xbf, Wl, Wr, WT, (uint4*)(ws + z0), zq);
    count_deg<<<(N_EDGES + 255) / 256, 256, 0, stream>>>(dstp, rowptr);
    scan_excl<<<1, 1024, 0, stream>>>(rowptr, cursor);
    scatter_edges<<<(ETOT + 255) / 256, 256, 0, stream>>>(srcp, dstp, cursor, colidx);

    for (int l = 0; l < NLAYER; ++l) {
        const u16* Asrc = (l == 0) ? xbf : hbf;
        gemm_mfma<<<dim3(157, 4), 256, 0, stream>>>(Asrc, WT + (size_t)l * 512 * 256,
                                                    bl + l * 256, br + l * 256, xlb, xrb);
        gat_agg<<<5000, 256, 0, stream>>>(xlb, xrb, rowptr, colidx, att + l * 256, cb + l * 256,
                                          hB, slots + (size_t)l * NSLOT * 512);
        if (l < NLAYER - 1) {
            fin_stats<<<1, 256, 0, stream>>>(slots + (size_t)l * NSLOT * 512, nw, nb, na, wcbb);
            norm_prelu<<<2500, 256, 0, stream>>>(hB, hbf, wcbb, pa, l);
        }
    }
    pool_kernel<<<200, 256, 0, stream>>>(hB, batch, slots + (size_t)2 * NSLOT * 512,
                                         nw, nb, na, pa, pooled);
    pool_norm<<<1, 256, 0, stream>>>(pooled, nw, nb, na, pn);
    fc_kernel<<<NBATCH, 256, 0, stream>>>(pn, fcW, fcb, out);
}